// Round 1
// baseline (719.250 us; speedup 1.0000x reference)
//
#include <hip/hip_runtime.h>
#include <math.h>

#define NN 8192
#define NE 65536
#define NG 16
#define NEL 10
#define CC 64
#define NLM 16
#define PI_D 3.14159265358979323846

// l index for each lm: 0 | 1 1 1 | 2 2 2 2 2 | 3 3 3 3 3 3 3
__device__ __forceinline__ int lm_l(int lm) {
    return (lm == 0) ? 0 : (lm < 4) ? 1 : (lm < 9) ? 2 : 3;
}

// ---------------- geometry forward: vec, length, u, Y(16), R(8) ----------------
__global__ void k_geom(const float* __restrict__ pos, const float* __restrict__ shifts,
                       const int* __restrict__ snd, const int* __restrict__ rcv,
                       float* __restrict__ Y, float* __restrict__ R,
                       float* __restrict__ U, float* __restrict__ L)
{
    int e = blockIdx.x * blockDim.x + threadIdx.x;
    if (e >= NE) return;
    int s = snd[e], r = rcv[e];
    float vx = pos[r*3+0] - pos[s*3+0] + shifts[e*3+0];
    float vy = pos[r*3+1] - pos[s*3+1] + shifts[e*3+1];
    float vz = pos[r*3+2] - pos[s*3+2] + shifts[e*3+2];
    float len = sqrtf(vx*vx + vy*vy + vz*vz + 1e-9f);
    float x = vx/len, y = vy/len, z = vz/len;
    U[e*3+0] = x; U[e*3+1] = y; U[e*3+2] = z; L[e] = len;
    float x2 = x*x, y2 = y*y, z2 = z*z;
    float* Ye = Y + e*16;
    Ye[0]  = 0.28209479177387814f;
    Ye[1]  = 0.4886025119029199f*y;
    Ye[2]  = 0.4886025119029199f*z;
    Ye[3]  = 0.4886025119029199f*x;
    Ye[4]  = 1.0925484305920792f*x*y;
    Ye[5]  = 1.0925484305920792f*y*z;
    Ye[6]  = 0.31539156525252005f*(3.f*z2 - 1.f);
    Ye[7]  = 1.0925484305920792f*x*z;
    Ye[8]  = 0.5462742152960396f*(x2 - y2);
    Ye[9]  = 0.5900435899266435f*y*(3.f*x2 - y2);
    Ye[10] = 2.890611442640554f*x*y*z;
    Ye[11] = 0.4570457994644658f*y*(5.f*z2 - 1.f);
    Ye[12] = 0.3731763325901154f*z*(5.f*z2 - 3.f);
    Ye[13] = 0.4570457994644658f*x*(5.f*z2 - 1.f);
    Ye[14] = 1.445305721320277f*z*(x2 - y2);
    Ye[15] = 0.5900435899266435f*x*(x2 - 3.f*y2);
    // radial in double (matches fp64 np reference closely; sin/r cancellation-safe)
    double Ld = (double)len;
    double ur = Ld / 5.0;
    double cut = 0.0;
    if (ur < 1.0) {
        double u5 = ur*ur*ur*ur*ur, u6 = u5*ur, u7 = u6*ur;
        cut = 1.0 - 21.0*u5 + 35.0*u6 - 15.0*u7;
    }
    double s2 = sqrt(0.4);
    for (int nb = 0; nb < 8; nb++) {
        double kn = (double)(nb+1) * PI_D / 5.0;
        R[e*8+nb] = (float)(s2 * sin(kn*Ld) / Ld * cut);
    }
}

// ---------------- node init: h0 = attrs@W_embed, elem, e0 -> out ----------------
__global__ void k_node_init(const float* __restrict__ attrs, const float* __restrict__ Wemb,
                            const float* __restrict__ aew, const int* __restrict__ batch,
                            float* __restrict__ h0, int* __restrict__ elem, float* __restrict__ out)
{
    int n = blockIdx.x, c = threadIdx.x;
    float hv = 0.f;
    for (int el = 0; el < NEL; el++) hv += attrs[n*NEL+el] * Wemb[el*CC+c];
    h0[n*CC+c] = hv;
    if (c == 0) {
        int el = 0; float e0 = 0.f;
        for (int k = 0; k < NEL; k++) {
            float a = attrs[n*NEL+k];
            e0 += a * aew[k];
            if (a > 0.5f) el = k;
        }
        elem[n] = el;
        atomicAdd(&out[batch[n]], e0);
    }
}

// ---------------- counting sort by rcv ----------------
__global__ void k_count(const int* __restrict__ rcv, int* __restrict__ cnt)
{
    int e = blockIdx.x * blockDim.x + threadIdx.x;
    if (e < NE) atomicAdd(&cnt[rcv[e]], 1);
}

__global__ void k_scan(const int* __restrict__ cnt, int* __restrict__ offs)
{
    __shared__ int s[1024];
    int t = threadIdx.x;
    int loc[8];
    int run = 0;
    for (int i = 0; i < 8; i++) {
        int v = cnt[t*8+i];
        loc[i] = run; run += v;
    }
    s[t] = run;
    __syncthreads();
    for (int o = 1; o < 1024; o <<= 1) {
        int v = 0;
        if (t >= o) v = s[t-o];
        __syncthreads();
        s[t] += v;
        __syncthreads();
    }
    int prev = (t == 0) ? 0 : s[t-1];
    for (int i = 0; i < 8; i++) offs[t*8+i] = prev + loc[i];
    if (t == 1023) offs[NN] = prev + run;
}

__global__ void k_scatter(const int* __restrict__ rcv, const int* __restrict__ offs,
                          int* __restrict__ cur, int* __restrict__ ebr)
{
    int e = blockIdx.x * blockDim.x + threadIdx.x;
    if (e >= NE) return;
    int r = rcv[e];
    int p = offs[r] + atomicAdd(&cur[r], 1);
    ebr[p] = e;
}

// ---------------- layer forward: A = seg_sum(msg), B, h_next ----------------
__global__ __launch_bounds__(64) void k_fwd(
    const float* __restrict__ Y, const float* __restrict__ R,
    const float* __restrict__ Wrad,   // layer base: [8][64]
    const float* __restrict__ Wprod,  // layer base: [10][256][64]
    const float* __restrict__ hprev, const float* __restrict__ attrs,
    const int* __restrict__ elem, const int* __restrict__ offs,
    const int* __restrict__ ebr, const int* __restrict__ snd,
    float* __restrict__ A, float* __restrict__ hnext)
{
    int n = blockIdx.x, c = threadIdx.x;
    float wr[8];
#pragma unroll
    for (int nb = 0; nb < 8; nb++) wr[nb] = Wrad[nb*CC+c];
    float acc[NLM];
#pragma unroll
    for (int lm = 0; lm < NLM; lm++) acc[lm] = 0.f;
    int beg = offs[n], end = offs[n+1];
    for (int j = beg; j < end; j++) {
        int e = ebr[j];
        int s = snd[e];
        float wv = 0.f;
#pragma unroll
        for (int nb = 0; nb < 8; nb++) wv += R[e*8+nb] * wr[nb];
        float wh = wv * hprev[s*CC+c];
#pragma unroll
        for (int lm = 0; lm < NLM; lm++) acc[lm] += Y[e*16+lm] * wh;
    }
#pragma unroll
    for (int lm = 0; lm < NLM; lm++) A[n*1024 + lm*CC + c] = acc[lm];
    __shared__ float Bs[256];
    float b0 = acc[0]*acc[0];
    float b1 = acc[1]*acc[1] + acc[2]*acc[2] + acc[3]*acc[3];
    float b2 = acc[4]*acc[4] + acc[5]*acc[5] + acc[6]*acc[6] + acc[7]*acc[7] + acc[8]*acc[8];
    float b3 = 0.f;
#pragma unroll
    for (int lm = 9; lm < 16; lm++) b3 += acc[lm]*acc[lm];
    Bs[c] = b0; Bs[64+c] = b1; Bs[128+c] = b2; Bs[192+c] = b3;
    __syncthreads();
    int el = elem[n];
    float a = attrs[n*NEL+el];
    const float* Wn = Wprod + el*256*CC;
    float hv = 0.f;
    for (int f = 0; f < 256; f++) hv += Bs[f] * Wn[f*CC + c];
    hnext[n*CC+c] = a * hv;
}

// ---------------- vB1[el][f] = sum_c w_read[c]*Wprod1[el][f][c] ----------------
__global__ void k_vb1(const float* __restrict__ Wprod1, const float* __restrict__ wread,
                      float* __restrict__ vb1)
{
    int el = blockIdx.x, f = threadIdx.x;
    float s = 0.f;
    for (int c = 0; c < CC; c++) s += wread[c] * Wprod1[el*256*CC + f*CC + c];
    vb1[el*256+f] = s;
}

// ---------------- gB (layer1) = attrs . vB1 ----------------
__global__ __launch_bounds__(64) void k_gb1(const float* __restrict__ attrs, const float* __restrict__ vb1,
                                            float* __restrict__ gB)
{
    int n = blockIdx.x, t = threadIdx.x;
    for (int j = 0; j < 4; j++) {
        int f = t + 64*j;
        float s = 0.f;
        for (int el = 0; el < NEL; el++) s += attrs[n*NEL+el] * vb1[el*256+f];
        gB[n*256+f] = s;
    }
}

// ---------------- gB (layer0) from g_h1 and Wprod0 ----------------
__global__ __launch_bounds__(64) void k_gb0(const float* __restrict__ gh1, const float* __restrict__ Wprod0,
                                            const float* __restrict__ attrs, const int* __restrict__ elem,
                                            float* __restrict__ gB)
{
    int n = blockIdx.x, t = threadIdx.x;
    __shared__ float gs[64];
    gs[t] = gh1[n*CC+t];
    __syncthreads();
    int el = elem[n];
    float a = attrs[n*NEL+el];
    const float* Wn = Wprod0 + el*256*CC;
    for (int j = 0; j < 4; j++) {
        int f = t + 64*j;
        float s = 0.f;
        for (int c = 0; c < CC; c++) s += gs[c] * Wn[f*CC + c];
        gB[n*256+f] = a * s;
    }
}

// ---------------- per-edge backward for one layer ----------------
__global__ __launch_bounds__(64) void k_edge_bwd(
    const float* __restrict__ Y, const float* __restrict__ R,
    const float* __restrict__ Wrad,      // layer base
    const float* __restrict__ A,         // this layer's A
    const float* __restrict__ gB,        // this layer's gB
    const float* __restrict__ hprev,
    const int* __restrict__ snd, const int* __restrict__ rcv,
    float* __restrict__ gY, float* __restrict__ gR, float* __restrict__ gh,
    int do_gh, int accum)
{
    int e = blockIdx.x, c = threadIdx.x;
    int sn = snd[e], rn = rcv[e];
    float wr[8];
#pragma unroll
    for (int nb = 0; nb < 8; nb++) wr[nb] = Wrad[nb*CC+c];
    float wv = 0.f;
#pragma unroll
    for (int nb = 0; nb < 8; nb++) wv += R[e*8+nb] * wr[nb];
    float hv = hprev[sn*CC+c];
    float Ys[NLM];
#pragma unroll
    for (int lm = 0; lm < NLM; lm++) Ys[lm] = Y[e*16+lm];
    const float* Ar = A + rn*1024;
    const float* gBr = gB + rn*256;
    float g4[4];
#pragma unroll
    for (int l = 0; l < 4; l++) g4[l] = gBr[l*CC+c];
    float gw = 0.f, ghv = 0.f;
    float p[NLM];
#pragma unroll
    for (int lm = 0; lm < NLM; lm++) {
        int l = lm_l(lm);
        float ga = 2.f * Ar[lm*CC+c] * g4[l];
        gw  += ga * hv * Ys[lm];
        ghv += ga * wv * Ys[lm];
        p[lm] = ga * wv * hv;
    }
    // reduce p[lm] over 64 lanes (butterfly)
    for (int o = 32; o > 0; o >>= 1) {
#pragma unroll
        for (int lm = 0; lm < NLM; lm++) p[lm] += __shfl_xor(p[lm], o, 64);
    }
    if (c == 0) {
        if (accum) {
#pragma unroll
            for (int lm = 0; lm < NLM; lm++) gY[e*16+lm] += p[lm];
        } else {
#pragma unroll
            for (int lm = 0; lm < NLM; lm++) gY[e*16+lm] = p[lm];
        }
    }
    float q[8];
#pragma unroll
    for (int nb = 0; nb < 8; nb++) q[nb] = gw * wr[nb];
    for (int o = 32; o > 0; o >>= 1) {
#pragma unroll
        for (int nb = 0; nb < 8; nb++) q[nb] += __shfl_xor(q[nb], o, 64);
    }
    if (c == 0) {
        if (accum) {
#pragma unroll
            for (int nb = 0; nb < 8; nb++) gR[e*8+nb] += q[nb];
        } else {
#pragma unroll
            for (int nb = 0; nb < 8; nb++) gR[e*8+nb] = q[nb];
        }
    }
    if (do_gh) atomicAdd(&gh[sn*CC+c], ghv);
}

// ---------------- geometry backward: gY,gR -> force atomics ----------------
__global__ void k_geo_bwd(const float* __restrict__ gY, const float* __restrict__ gR,
                          const float* __restrict__ U, const float* __restrict__ L,
                          const int* __restrict__ snd, const int* __restrict__ rcv,
                          float* __restrict__ F)
{
    int e = blockIdx.x * blockDim.x + threadIdx.x;
    if (e >= NE) return;
    float x = U[e*3+0], y = U[e*3+1], z = U[e*3+2];
    float len = L[e];
    const float* g = gY + e*16;
    float x2 = x*x, y2 = y*y, z2 = z*z;
    float gx = 0.f, gy = 0.f, gz = 0.f;
    gx += 0.4886025119029199f*g[3];
    gy += 0.4886025119029199f*g[1];
    gz += 0.4886025119029199f*g[2];
    gx += 1.0925484305920792f*y*g[4];  gy += 1.0925484305920792f*x*g[4];
    gy += 1.0925484305920792f*z*g[5];  gz += 1.0925484305920792f*y*g[5];
    gz += 1.8923493915151203f*z*g[6];                      // 6*c20
    gx += 1.0925484305920792f*z*g[7];  gz += 1.0925484305920792f*x*g[7];
    gx += 1.0925484305920792f*x*g[8];  gy -= 1.0925484305920792f*y*g[8];   // 2*c22
    gx += 3.540261539559861f*x*y*g[9];                     // 6*c3a
    gy += 0.5900435899266435f*(3.f*x2 - 3.f*y2)*g[9];
    gx += 2.890611442640554f*y*z*g[10]; gy += 2.890611442640554f*x*z*g[10]; gz += 2.890611442640554f*x*y*g[10];
    gy += 0.4570457994644658f*(5.f*z2 - 1.f)*g[11]; gz += 4.570457994644658f*y*z*g[11];
    gz += 0.3731763325901154f*(15.f*z2 - 3.f)*g[12];
    gx += 0.4570457994644658f*(5.f*z2 - 1.f)*g[13]; gz += 4.570457994644658f*x*z*g[13];
    gx += 2.890611442640554f*x*z*g[14]; gy -= 2.890611442640554f*y*z*g[14]; // 2*c3e
    gz += 1.445305721320277f*(x2 - y2)*g[14];
    gx += 0.5900435899266435f*(3.f*x2 - 3.f*y2)*g[15];
    gy -= 3.540261539559861f*x*y*g[15];
    // radial part in double (cancellation-prone at small r)
    double Ld = (double)len, ur = Ld / 5.0;
    double gL = 0.0;
    if (ur < 1.0) {
        double u4 = ur*ur*ur*ur, u5 = u4*ur, u6 = u5*ur, u7 = u6*ur;
        double poly  = 1.0 - 21.0*u5 + 35.0*u6 - 15.0*u7;
        double dpoly = (-105.0*u4 + 210.0*u5 - 105.0*u6) / 5.0;
        double s2 = sqrt(0.4);
        for (int nb = 0; nb < 8; nb++) {
            double kn = (double)(nb+1) * PI_D / 5.0;
            double sn_ = sin(kn*Ld), cs = cos(kn*Ld);
            double bes  = s2*sn_/Ld;
            double dbes = s2*(kn*cs/Ld - sn_/(Ld*Ld));
            gL += (double)gR[e*8+nb] * (dbes*poly + bes*dpoly);
        }
    }
    float gLf = (float)gL;
    float dot = gx*x + gy*y + gz*z;
    float gvx = (gx - dot*x)/len + gLf*x;
    float gvy = (gy - dot*y)/len + gLf*y;
    float gvz = (gz - dot*z)/len + gLf*z;
    int sn = snd[e], rn = rcv[e];
    atomicAdd(&F[rn*3+0], -gvx);
    atomicAdd(&F[rn*3+1], -gvy);
    atomicAdd(&F[rn*3+2], -gvz);
    atomicAdd(&F[sn*3+0],  gvx);
    atomicAdd(&F[sn*3+1],  gvy);
    atomicAdd(&F[sn*3+2],  gvz);
}

// ---------------- final readout: node_e -> out[batch] ----------------
__global__ void k_final(const float* __restrict__ h2, const float* __restrict__ wread,
                        const int* __restrict__ batch, float* __restrict__ out)
{
    int n = blockIdx.x * blockDim.x + threadIdx.x;
    if (n >= NN) return;
    float s = 0.f;
    for (int c = 0; c < CC; c++) s += h2[n*CC+c] * wread[c];
    atomicAdd(&out[batch[n]], s);
}

extern "C" void kernel_launch(void* const* d_in, const int* in_sizes, int n_in,
                              void* d_out, int out_size, void* d_ws, size_t ws_size,
                              hipStream_t stream)
{
    const float* positions  = (const float*)d_in[0];
    const float* node_attrs = (const float*)d_in[1];
    const float* shifts     = (const float*)d_in[2];
    const float* W_embed    = (const float*)d_in[3];
    const float* aew        = (const float*)d_in[4];
    const float* W_rad      = (const float*)d_in[5];  // [2][8][64]
    const float* W_prod     = (const float*)d_in[6];  // [2][10][256][64]
    const float* w_read     = (const float*)d_in[7];
    const int*   edge_index = (const int*)d_in[8];    // [2][E]
    const int*   batch      = (const int*)d_in[9];
    float* out = (float*)d_out;                        // [16 energy][8192*3 forces]

    const int* snd = edge_index;
    const int* rcv = edge_index + NE;

    char* ws = (char*)d_ws;
    size_t off = 0;
    auto allocf = [&](size_t nelems) -> float* {
        float* p = (float*)(ws + off); off += nelems * sizeof(float); return p;
    };
    float* Y    = allocf((size_t)NE*16);
    float* R    = allocf((size_t)NE*8);
    float* U    = allocf((size_t)NE*3);
    float* L    = allocf((size_t)NE);
    float* H0   = allocf((size_t)NN*CC);
    float* H1   = allocf((size_t)NN*CC);
    float* H2   = allocf((size_t)NN*CC);
    float* Abuf = allocf((size_t)NN*1024);
    float* GB   = allocf((size_t)NN*256);
    float* GH1  = allocf((size_t)NN*CC);
    float* GY   = allocf((size_t)NE*16);
    float* GR   = allocf((size_t)NE*8);
    float* VB1  = allocf((size_t)NEL*256);
    int* ELEM = (int*)(ws + off); off += (size_t)NN*4;
    int* CNT  = (int*)(ws + off); off += (size_t)NN*4;
    int* CUR  = (int*)(ws + off); off += (size_t)NN*4;
    int* OFFS = (int*)(ws + off); off += (size_t)(NN+1)*4;
    int* EBR  = (int*)(ws + off); off += (size_t)NE*4;

    // zero-init accumulation targets (harness poisons with 0xAA every call)
    hipMemsetAsync(out, 0, (size_t)out_size * sizeof(float), stream);
    hipMemsetAsync(CNT, 0, (size_t)NN*4, stream);
    hipMemsetAsync(CUR, 0, (size_t)NN*4, stream);
    hipMemsetAsync(GH1, 0, (size_t)NN*CC*4, stream);

    const float* Wrad0  = W_rad;
    const float* Wrad1  = W_rad + 8*CC;
    const float* Wprod0 = W_prod;
    const float* Wprod1 = W_prod + (size_t)NEL*256*CC;

    k_geom<<<NE/256, 256, 0, stream>>>(positions, shifts, snd, rcv, Y, R, U, L);
    k_node_init<<<NN, 64, 0, stream>>>(node_attrs, W_embed, aew, batch, H0, ELEM, out);
    k_count<<<NE/256, 256, 0, stream>>>(rcv, CNT);
    k_scan<<<1, 1024, 0, stream>>>(CNT, OFFS);
    k_scatter<<<NE/256, 256, 0, stream>>>(rcv, OFFS, CUR, EBR);

    // forward layer 0: H0 -> A0, H1
    k_fwd<<<NN, 64, 0, stream>>>(Y, R, Wrad0, Wprod0, H0, node_attrs, ELEM, OFFS, EBR, snd, Abuf, H1);
    // forward layer 1: H1 -> A1, H2
    k_fwd<<<NN, 64, 0, stream>>>(Y, R, Wrad1, Wprod1, H1, node_attrs, ELEM, OFFS, EBR, snd, Abuf, H2);

    // backward
    k_vb1<<<NEL, 256, 0, stream>>>(Wprod1, w_read, VB1);
    k_gb1<<<NN, 64, 0, stream>>>(node_attrs, VB1, GB);
    // layer 1 edge backward (Abuf holds A1): writes GY/GR, scatters GH1
    k_edge_bwd<<<NE, 64, 0, stream>>>(Y, R, Wrad1, Abuf, GB, H1, snd, rcv, GY, GR, GH1, 1, 0);
    // gB for layer 0 from GH1
    k_gb0<<<NN, 64, 0, stream>>>(GH1, Wprod0, node_attrs, ELEM, GB);
    // recompute A0 into Abuf (rewrites H1 with identical values)
    k_fwd<<<NN, 64, 0, stream>>>(Y, R, Wrad0, Wprod0, H0, node_attrs, ELEM, OFFS, EBR, snd, Abuf, H1);
    // layer 0 edge backward: accumulates GY/GR, no gh
    k_edge_bwd<<<NE, 64, 0, stream>>>(Y, R, Wrad0, Abuf, GB, H0, snd, rcv, GY, GR, GH1, 0, 1);
    // geometry backward -> forces
    k_geo_bwd<<<NE/256, 256, 0, stream>>>(GY, GR, U, L, snd, rcv, out + NG);
    // energy readout
    k_final<<<NN/256, 256, 0, stream>>>(H2, w_read, batch, out);
    (void)in_sizes; (void)n_in; (void)ws_size;
}